// Round 7
// baseline (251.997 us; speedup 1.0000x reference)
//
#include <hip/hip_runtime.h>
#include <hip/hip_bf16.h>
#include <stdint.h>

typedef __hip_bfloat16 bf16;
typedef __attribute__((ext_vector_type(8))) short v8s;   // 8 bf16 in 4 VGPRs
typedef __attribute__((ext_vector_type(4))) float v4f;   // MFMA C/D frag

__device__ __forceinline__ bf16 tob(float x) { return __float2bfloat16(x); }

// Sum over each aligned 16-lane group via DPP (VALU pipe, no LDS crossbar).
__device__ __forceinline__ float red16(float v) {
  v += __int_as_float(__builtin_amdgcn_update_dpp(0, __float_as_int(v), 0xB1, 0xF, 0xF, true));
  v += __int_as_float(__builtin_amdgcn_update_dpp(0, __float_as_int(v), 0x4E, 0xF, 0xF, true));
  v += __int_as_float(__builtin_amdgcn_update_dpp(0, __float_as_int(v), 0x141, 0xF, 0xF, true));
  v += __int_as_float(__builtin_amdgcn_update_dpp(0, __float_as_int(v), 0x140, 0xF, 0xF, true));
  return v;
}

// ============ fused input-only preprocessing (1 launch) ============
// blocks 0..511   : h1 = relu(fea @ W_l1 + b_l1)         (8,1024), K=1024
// blocks 512..767 : gp[b,n] = fea[b] @ W_c1[5:,n] + bc1  (8,512),  K=1024
// blocks 768..1023: W2T[n,k] = bf16(W_c2[k,n])           (512,512) plain transpose
// block  1024     : G[g,k] = gx*Wc1[0,k] + gy*Wc1[1,k]   (16,512)
__global__ void k_pre(const float* __restrict__ fea, const float* __restrict__ Wl1,
                      const float* __restrict__ bl1, const float* __restrict__ Wc1,
                      const float* __restrict__ bc1, const float* __restrict__ Wc2,
                      float* __restrict__ h1, float* __restrict__ gp,
                      bf16* __restrict__ WT, float* __restrict__ G) {
  __shared__ __align__(16) float sm[32 * 33 + 32];
  const int bid = blockIdx.x;
  if (bid < 512) {                     // ---- lin1 ----
    float* red = sm;
    const int nl = threadIdx.x & 15, ks = threadIdx.x >> 4;
    const int o = bid * 16 + nl;
    const int b = o >> 10, n = o & 1023;
    const float* fr = fea + (b << 10) + ks * 64;
    const float* wp = Wl1 + (size_t)(ks * 64) * 1024 + n;
    float acc = 0.f;
#pragma unroll 8
    for (int j = 0; j < 64; ++j)
      acc = fmaf(fr[j], wp[(size_t)j * 1024], acc);
    red[threadIdx.x] = acc;
    __syncthreads();
    if (threadIdx.x < 16) {
      float s = bl1[n];
#pragma unroll
      for (int i = 0; i < 16; ++i) s += red[i * 16 + threadIdx.x];
      h1[o] = fmaxf(s, 0.f);
    }
  } else if (bid < 768) {              // ---- gp ----
    float* red = sm;
    const int nl = threadIdx.x & 15, ks = threadIdx.x >> 4;
    const int o = (bid - 512) * 16 + nl;
    const int b = o >> 9, n = o & 511;
    const float* fr = fea + (b << 10) + ks * 64;
    const float* wp = Wc1 + (size_t)(5 + ks * 64) * 512 + n;
    float acc = 0.f;
#pragma unroll 8
    for (int j = 0; j < 64; ++j)
      acc = fmaf(fr[j], wp[(size_t)j * 512], acc);
    red[threadIdx.x] = acc;
    __syncthreads();
    if (threadIdx.x < 16) {
      float s = bc1[n];
#pragma unroll
      for (int i = 0; i < 16; ++i) s += red[i * 16 + threadIdx.x];
      gp[o] = s;
    }
  } else if (bid < 1024) {             // ---- w2t (plain transpose, bf16) ----
    float (*tile)[33] = (float(*)[33])sm;
    const int bb = bid - 768;
    int bx = bb & 15, by = bb >> 4;
    int c = threadIdx.x & 31, r8 = threadIdx.x >> 5;
#pragma unroll
    for (int i = 0; i < 4; ++i) {
      int r = r8 + i * 8;
      tile[r][c] = Wc2[(by * 32 + r) * 512 + bx * 32 + c];
    }
    __syncthreads();
#pragma unroll
    for (int i = 0; i < 4; ++i) {
      int r = r8 + i * 8;
      int n = bx * 32 + r;                       // output row (conv2 in-chan)
      int k = by * 32 + c;                       // original k
      WT[(size_t)n * 512 + k] = tob(tile[c][r]);
    }
  } else {                             // ---- grid table ----
    for (int e = threadIdx.x; e < 8192; e += 256) {
      int g = e >> 9, k = e & 511;
      const float gx = -0.05f + (float)(g & 3) * (0.1f / 3.0f);
      const float gy = -0.05f + (float)(g >> 2) * (0.1f / 3.0f);
      G[e] = fmaf(gy, Wc1[512 + k], gx * Wc1[k]);
    }
  }
}

// x = h1 @ W_l2 + b_l2   (8,3072), K=1024 -> xf (ws) + xout (d_out)
__global__ void k_lin2(const float* __restrict__ h1, const float* __restrict__ W,
                       const float* __restrict__ bias, float* __restrict__ xf,
                       float* __restrict__ xout) {
  __shared__ float red[256];
  const int nl = threadIdx.x & 15, ks = threadIdx.x >> 4;
  const int o = blockIdx.x * 16 + nl;            // 0..24575, same b within block
  const int b = o / 3072, n = o - b * 3072;
  const float* hr = h1 + (b << 10) + ks * 64;
  const float* wp = W + (size_t)(ks * 64) * 3072 + n;
  float acc = 0.f;
#pragma unroll 8
  for (int j = 0; j < 64; ++j)
    acc = fmaf(hr[j], wp[(size_t)j * 3072], acc);
  red[threadIdx.x] = acc;
  __syncthreads();
  if (threadIdx.x < 16) {
    float s = bias[n];
#pragma unroll
    for (int i = 0; i < 16; ++i) s += red[i * 16 + threadIdx.x];
    xf[o] = s;
    xout[o] = s;
  }
}

// ============ fused conv1+conv2 GEMM + conv3 epilogue ============
// 2048 blocks x 512 threads. Block: rows m0..m0+127, N-half nblk*256..+255,
// K=512, BK=32.
// ROUND-7 RESTRUCTURE: B is NOT staged in LDS. W2T is 512 KB (L2-resident);
// each block's per-kt B set is 16 KB (L1-fits). B fragments are loaded
// straight global->VGPR (16 rows x 4x16B slots = perfect 64B lines, 1 KB per
// load instruction). This removes the B LDS round-trip (48 KB/kt of the
// 89 KB/kt LDS traffic - the measured round-6 bottleneck) and shrinks LDS to
// 33.5 KB -> 4 blocks/CU (32 waves), whose TLP hides B's L1/L2 latency.
// LDS now holds only the A double-buffer (computed on the fly, 16B-slot
// swizzled by (row>>1)&3, bank-conflict-free) + Ps + facc.
// LAUNCH-BOUNDS RULE (measured twice): (512,6)+ truncates VGPR below demand ->
// scratch-spill disaster (rounds 1 & 4). Keep (512,4); natural use has been
// 52-60 for three rounds; <=64 is what unlocks 8 waves/SIMD.
// Epilogue conv3: DPP 16-lane reduce -> facc (LDS) -> global atomicAdd.
__global__ __launch_bounds__(512, 4)
void k_gemm(const bf16* __restrict__ W2T, const float* __restrict__ gp,
            const float* __restrict__ G, const float* __restrict__ Wc1,
            const float* __restrict__ xf, const float* __restrict__ bc2,
            const float* __restrict__ Wc3, const float* __restrict__ bc3,
            float* __restrict__ fine) {
  __shared__ __align__(16) bf16 As[2][128 * 32];   // 2 x 8 KB
  __shared__ __align__(16) float Ps[8][512];       // 16 KB
  __shared__ float facc[128][3];                   // 1.5 KB
  const int t = threadIdx.x;
  const int mblk = blockIdx.x >> 1, nblk = blockIdx.x & 1;
  const int m0 = mblk * 128;
  const int w = t >> 6, l = t & 63, q = l >> 4, lm = l & 15;
  const int wm = (w >> 2) * 64;          // wave output-row base (0 or 64)
  const int wn = (w & 3) * 64;           // wave output-col base within N-half
  const int qs = (q ^ ((lm >> 1) & 3)) << 4;  // swizzled 16B slot for A frag reads

  if (t < 384) ((float*)facc)[t] = 0.f;

  // ---- A-compute role: thread -> (row arow, k-subgroup cg of 8) ----
  const int arow = t >> 2, cg = t & 3;
  const int m = m0 + arow;
  const int b = m >> 14;                 // batch, uniform per block
  const int f = m & 16383;
  const int g = f & 15;
  const float* gr = G + (g << 9);                       // G row (512 f32)
  const float* pl = Ps[arow >> 4];                      // local P row in LDS
  char* awr = (char*)As + arow * 64 + ((cg ^ ((arow >> 1) & 3)) << 4); // + buf*8192

  // ---- P prologue: Ps[cl][k] = gp[b][k] + x·Wc1[2:5][k], 8 elems/thread ----
  {
    const int cl = t >> 6;               // local coarse point 0..7
    const int k8 = (t & 63) * 8;
    const int cglob = ((m0 & 16383) >> 4) + cl;
    const float* xq = xf + (b * 1024 + cglob) * 3;
    const float x0 = xq[0], x1 = xq[1], x2 = xq[2];
    const float* gpb = gp + (b << 9) + k8;
    float4 gv0 = *(const float4*)(gpb);
    float4 gv1 = *(const float4*)(gpb + 4);
    float4 w20 = *(const float4*)(Wc1 + 2 * 512 + k8);
    float4 w21 = *(const float4*)(Wc1 + 2 * 512 + k8 + 4);
    float4 w30 = *(const float4*)(Wc1 + 3 * 512 + k8);
    float4 w31 = *(const float4*)(Wc1 + 3 * 512 + k8 + 4);
    float4 w40 = *(const float4*)(Wc1 + 4 * 512 + k8);
    float4 w41 = *(const float4*)(Wc1 + 4 * 512 + k8 + 4);
    float4 r0, r1;
#pragma unroll
    for (int j = 0; j < 4; ++j) {
      ((float*)&r0)[j] = fmaf(x2, ((const float*)&w40)[j],
                         fmaf(x1, ((const float*)&w30)[j],
                         fmaf(x0, ((const float*)&w20)[j], ((const float*)&gv0)[j])));
      ((float*)&r1)[j] = fmaf(x2, ((const float*)&w41)[j],
                         fmaf(x1, ((const float*)&w31)[j],
                         fmaf(x0, ((const float*)&w21)[j], ((const float*)&gv1)[j])));
    }
    *(float4*)&Ps[cl][k8] = r0;
    *(float4*)&Ps[cl][k8 + 4] = r1;
  }

  // ---- B fragment source: row = nblk*256 + wn + ni*16 + lm, k = kt*32 + q*8 ----
  const bf16* wrow = W2T + (size_t)(nblk * 256 + wn + lm) * 512 + q * 8;

  v4f acc[4][4];
#pragma unroll
  for (int mi = 0; mi < 4; ++mi)
#pragma unroll
    for (int ni = 0; ni < 4; ++ni) acc[mi][ni] = (v4f){0.f, 0.f, 0.f, 0.f};

  // A-tile stage: relu(P + G) -> bf16 -> swizzled LDS slot. Pure
  // {2 broadcast ds_read + 2 L1-hot global + ~20 VALU + 1 ds_write}.
  auto stage = [&](int kt, int buf) {
    const int kk = kt * 32 + cg * 8;
    float4 g0 = *(const float4*)(gr + kk);
    float4 g1 = *(const float4*)(gr + kk + 4);
    float4 p0 = *(const float4*)(pl + kk);
    float4 p1 = *(const float4*)(pl + kk + 4);
    union { bf16 h[8]; uint4 u; } o;
#pragma unroll
    for (int j = 0; j < 4; ++j) {
      o.h[j]     = tob(fmaxf(((const float*)&p0)[j] + ((const float*)&g0)[j], 0.f));
      o.h[4 + j] = tob(fmaxf(((const float*)&p1)[j] + ((const float*)&g1)[j], 0.f));
    }
    *(uint4*)(awr + buf * 8192) = o.u;
  };

  __syncthreads();                       // Ps visible to all waves
  stage(0, 0);

#pragma unroll 2
  for (int kt = 0; kt < 16; ++kt) {
    const int buf = kt & 1;
    __syncthreads();                     // stage(kt,buf) complete on all waves
    if (kt < 15) stage(kt + 1, buf ^ 1); // prefetch next A tile (other buffer)
    // B frags straight from global (L1/L2); A frags from LDS
    v8s af[4], bfr[4];
#pragma unroll
    for (int ni = 0; ni < 4; ++ni)
      bfr[ni] = *(const v8s*)(wrow + (size_t)ni * 16 * 512 + kt * 32);
    const char* ab = (const char*)As + buf * 8192;
#pragma unroll
    for (int mi = 0; mi < 4; ++mi)
      af[mi] = *(const v8s*)(ab + (wm + mi * 16 + lm) * 64 + qs);
#pragma unroll
    for (int mi = 0; mi < 4; ++mi)
#pragma unroll
      for (int ni = 0; ni < 4; ++ni)
        acc[mi][ni] = __builtin_amdgcn_mfma_f32_16x16x32_bf16(af[mi], bfr[ni], acc[mi][ni], 0, 0, 0);
  }

  // ---- epilogue: h2 = relu(acc + b_c2); fine partials via Wc3 ----
  float part[4][4][3];
#pragma unroll
  for (int mi = 0; mi < 4; ++mi)
#pragma unroll
    for (int r = 0; r < 4; ++r) { part[mi][r][0] = 0.f; part[mi][r][1] = 0.f; part[mi][r][2] = 0.f; }
#pragma unroll
  for (int ni = 0; ni < 4; ++ni) {
    const int n = nblk * 256 + wn + ni * 16 + lm;
    const float bv = bc2[n];
    const float w30 = Wc3[n * 3 + 0];
    const float w31 = Wc3[n * 3 + 1];
    const float w32 = Wc3[n * 3 + 2];
#pragma unroll
    for (int mi = 0; mi < 4; ++mi)
#pragma unroll
      for (int r = 0; r < 4; ++r) {
        float v = fmaxf(acc[mi][ni][r] + bv, 0.f);
        part[mi][r][0] = fmaf(v, w30, part[mi][r][0]);
        part[mi][r][1] = fmaf(v, w31, part[mi][r][1]);
        part[mi][r][2] = fmaf(v, w32, part[mi][r][2]);
      }
  }
#pragma unroll
  for (int mi = 0; mi < 4; ++mi)
#pragma unroll
    for (int r = 0; r < 4; ++r)
#pragma unroll
      for (int j = 0; j < 3; ++j) {
        float v = red16(part[mi][r][j]);   // DPP 16-lane sum (lm group)
        if (lm == 0) atomicAdd(&facc[wm + mi * 16 + q * 4 + r][j], v);
      }
  __syncthreads();
  if (t < 128) {
    const int mm = m0 + t;
    float* fp = fine + (size_t)mm * 3;
    float base[3] = {0.f, 0.f, 0.f};
    if (nblk == 0) {
      const int bb2 = mm >> 14, cc = (mm & 16383) >> 4;
      const float* xq = xf + (bb2 * 1024 + cc) * 3;
#pragma unroll
      for (int j = 0; j < 3; ++j) base[j] = bc3[j] + xq[j];
    }
#pragma unroll
    for (int j = 0; j < 3; ++j)
      atomicAdd(&fp[j], facc[t][j] + base[j]);
  }
}

extern "C" void kernel_launch(void* const* d_in, const int* in_sizes, int n_in,
                              void* d_out, int out_size, void* d_ws, size_t ws_size,
                              hipStream_t stream) {
  const float* fea = (const float*)d_in[0];
  const float* Wl1 = (const float*)d_in[1];
  const float* bl1 = (const float*)d_in[2];
  const float* Wl2 = (const float*)d_in[3];
  const float* bl2 = (const float*)d_in[4];
  const float* Wc1 = (const float*)d_in[5];
  const float* bc1 = (const float*)d_in[6];
  const float* Wc2 = (const float*)d_in[7];
  const float* bc2 = (const float*)d_in[8];
  const float* Wc3 = (const float*)d_in[9];
  const float* bc3 = (const float*)d_in[10];
  float* xout = (float*)d_out;                // (8,1024,3)
  float* fine = (float*)d_out + 24576;        // (8,16384,3)
  char* ws = (char*)d_ws;
  float* h1  = (float*)ws;                    // 32 KB
  float* xf  = (float*)(ws + 32768);          // 96 KB
  float* gp  = (float*)(ws + 131072);         // 16 KB
  bf16*  W2T = (bf16*)(ws + 147456);          // 512 KB
  float* G   = (float*)(ws + 671744);         // 32 KB

  hipMemsetAsync(fine, 0, (size_t)131072 * 3 * sizeof(float), stream);
  k_pre<<<1025, 256, 0, stream>>>(fea, Wl1, bl1, Wc1, bc1, Wc2, h1, gp, W2T, G);
  k_lin2<<<1536, 256, 0, stream>>>(h1, Wl2, bl2, xf, xout);
  k_gemm<<<2048, 512, 0, stream>>>(W2T, gp, G, Wc1, xf, bc2, Wc3, bc3, fine);
}

// Round 8
// 180.817 us; speedup vs baseline: 1.3937x; 1.3937x over previous
//
#include <hip/hip_runtime.h>
#include <hip/hip_bf16.h>
#include <stdint.h>

typedef __hip_bfloat16 bf16;
typedef __attribute__((ext_vector_type(8))) short v8s;   // 8 bf16 in 4 VGPRs
typedef __attribute__((ext_vector_type(4))) float v4f;   // MFMA C/D frag

__device__ __forceinline__ bf16 tob(float x) { return __float2bfloat16(x); }

// async global->LDS, 16B per lane; LDS dest must be wave-uniform base + lane*16
__device__ __forceinline__ void gload16(const void* g, void* l) {
  __builtin_amdgcn_global_load_lds(
      (const __attribute__((address_space(1))) uint32_t*)g,
      (__attribute__((address_space(3))) uint32_t*)l,
      16, 0, 0);
}

// Sum over each aligned 16-lane group via DPP (VALU pipe, no LDS crossbar).
__device__ __forceinline__ float red16(float v) {
  v += __int_as_float(__builtin_amdgcn_update_dpp(0, __float_as_int(v), 0xB1, 0xF, 0xF, true));
  v += __int_as_float(__builtin_amdgcn_update_dpp(0, __float_as_int(v), 0x4E, 0xF, 0xF, true));
  v += __int_as_float(__builtin_amdgcn_update_dpp(0, __float_as_int(v), 0x141, 0xF, 0xF, true));
  v += __int_as_float(__builtin_amdgcn_update_dpp(0, __float_as_int(v), 0x140, 0xF, 0xF, true));
  return v;
}

// ============ fused input-only preprocessing (1 launch) ============
// blocks 0..511    : h1 = relu(fea @ W_l1 + b_l1)         (8,1024), K=1024
// blocks 512..767  : gp[b,n] = fea[b] @ W_c1[5:,n] + bc1  (8,512),  K=1024
// blocks 768..1023 : W2T[n,k-swz] = bf16(W_c2[k,n])       (512,512), pre-swizzled
// block  1024      : G[g,k] = gx*Wc1[0,k] + gy*Wc1[1,k]   (16,512)
// blocks 1025..1408: fine = 0  (replaces hipMemsetAsync: one fewer dispatch)
__global__ void k_pre(const float* __restrict__ fea, const float* __restrict__ Wl1,
                      const float* __restrict__ bl1, const float* __restrict__ Wc1,
                      const float* __restrict__ bc1, const float* __restrict__ Wc2,
                      float* __restrict__ h1, float* __restrict__ gp,
                      bf16* __restrict__ WT, float* __restrict__ G,
                      float* __restrict__ fine) {
  __shared__ __align__(16) float sm[32 * 33 + 32];
  const int bid = blockIdx.x;
  if (bid < 512) {                     // ---- lin1 ----
    float* red = sm;
    const int nl = threadIdx.x & 15, ks = threadIdx.x >> 4;
    const int o = bid * 16 + nl;
    const int b = o >> 10, n = o & 1023;
    const float* fr = fea + (b << 10) + ks * 64;
    const float* wp = Wl1 + (size_t)(ks * 64) * 1024 + n;
    float acc = 0.f;
#pragma unroll 8
    for (int j = 0; j < 64; ++j)
      acc = fmaf(fr[j], wp[(size_t)j * 1024], acc);
    red[threadIdx.x] = acc;
    __syncthreads();
    if (threadIdx.x < 16) {
      float s = bl1[n];
#pragma unroll
      for (int i = 0; i < 16; ++i) s += red[i * 16 + threadIdx.x];
      h1[o] = fmaxf(s, 0.f);
    }
  } else if (bid < 768) {              // ---- gp ----
    float* red = sm;
    const int nl = threadIdx.x & 15, ks = threadIdx.x >> 4;
    const int o = (bid - 512) * 16 + nl;
    const int b = o >> 9, n = o & 511;
    const float* fr = fea + (b << 10) + ks * 64;
    const float* wp = Wc1 + (size_t)(5 + ks * 64) * 512 + n;
    float acc = 0.f;
#pragma unroll 8
    for (int j = 0; j < 64; ++j)
      acc = fmaf(fr[j], wp[(size_t)j * 512], acc);
    red[threadIdx.x] = acc;
    __syncthreads();
    if (threadIdx.x < 16) {
      float s = bc1[n];
#pragma unroll
      for (int i = 0; i < 16; ++i) s += red[i * 16 + threadIdx.x];
      gp[o] = s;
    }
  } else if (bid < 1024) {             // ---- w2t (pre-swizzled transpose) ----
    // 16B k-slot within each 64B K-block XOR-swizzled by ((n>>1)&3) so the
    // LINEAR gload16 copy lands bank-conflict-free for k_gemm's swizzled
    // ds_read_b128 (LDS dest of global_load_lds cannot be swizzled).
    float (*tile)[33] = (float(*)[33])sm;
    const int bb = bid - 768;
    int bx = bb & 15, by = bb >> 4;
    int c = threadIdx.x & 31, r8 = threadIdx.x >> 5;
#pragma unroll
    for (int i = 0; i < 4; ++i) {
      int r = r8 + i * 8;
      tile[r][c] = Wc2[(by * 32 + r) * 512 + bx * 32 + c];
    }
    __syncthreads();
#pragma unroll
    for (int i = 0; i < 4; ++i) {
      int r = r8 + i * 8;
      int n = bx * 32 + r;                       // output row (conv2 in-chan)
      int k = by * 32 + c;                       // original k
      int s = (c >> 3) & 3;                      // 16B slot in 64B K-block
      int ks = (k & ~24) | (((s ^ ((n >> 1) & 3)) & 3) << 3);
      WT[(size_t)n * 512 + ks] = tob(tile[c][r]);
    }
  } else if (bid == 1024) {            // ---- grid table ----
    for (int e = threadIdx.x; e < 8192; e += 256) {
      int g = e >> 9, k = e & 511;
      const float gx = -0.05f + (float)(g & 3) * (0.1f / 3.0f);
      const float gy = -0.05f + (float)(g >> 2) * (0.1f / 3.0f);
      G[e] = fmaf(gy, Wc1[512 + k], gx * Wc1[k]);
    }
  } else {                             // ---- zero fine (393216 floats) ----
    const int i = ((bid - 1025) * 256 + threadIdx.x) * 4;
    *(float4*)(fine + i) = (float4){0.f, 0.f, 0.f, 0.f};
  }
}

// x = h1 @ W_l2 + b_l2   (8,3072), K=1024 -> xf (ws) + xout (d_out)
__global__ void k_lin2(const float* __restrict__ h1, const float* __restrict__ W,
                       const float* __restrict__ bias, float* __restrict__ xf,
                       float* __restrict__ xout) {
  __shared__ float red[256];
  const int nl = threadIdx.x & 15, ks = threadIdx.x >> 4;
  const int o = blockIdx.x * 16 + nl;            // 0..24575, same b within block
  const int b = o / 3072, n = o - b * 3072;
  const float* hr = h1 + (b << 10) + ks * 64;
  const float* wp = W + (size_t)(ks * 64) * 3072 + n;
  float acc = 0.f;
#pragma unroll 8
  for (int j = 0; j < 64; ++j)
    acc = fmaf(hr[j], wp[(size_t)j * 3072], acc);
  red[threadIdx.x] = acc;
  __syncthreads();
  if (threadIdx.x < 16) {
    float s = bias[n];
#pragma unroll
    for (int i = 0; i < 16; ++i) s += red[i * 16 + threadIdx.x];
    xf[o] = s;
    xout[o] = s;
  }
}

// ============ fused conv1+conv2 GEMM + conv3 epilogue ============
// Round-6 structure (best measured: 91 us) + round-8 fix: G register-prefetch
// one phase ahead, ISSUED AFTER stage's gload16s.
// WHY: vmcnt retires IN ORDER. Round 6 issued [B gload16, G loads] then
// consumed G in the same phase -> waiting for G also drained the B prefetch:
// the "async" staging was fully synchronous, ~1 L2 round-trip exposed per kt.
// Now per-phase VMEM order is [B(kt+1), G(kt+2)]; stage consumes G loaded a
// full phase earlier (counted-wait keeps B in flight), and the barrier's
// vmcnt(0) drains only loads that have had ~a whole phase to complete.
// G is 32 KB L2/L1-hot so one phase always suffices (round-5's T14 failure
// was prefetching the 16 MB HBM P stream; P now lives in LDS: no such risk).
// LDS = 67072 B -> 2 blocks/CU. True reg demand ~116 (VGPR 52 + 64 acc AGPR,
// unified file) -> 4 waves/SIMD; 3 blocks/CU unreachable (round-7 lesson).
// LAUNCH-BOUNDS RULE (measured twice): (512,6) truncates VGPR below demand ->
// scratch-spill disaster (rounds 1 & 4). Keep (512,4).
// A k-slot swizzle (row>>1)&3 on write+read: bank-conflict-free (verified ~0).
// Epilogue conv3: DPP 16-lane reduce -> facc -> global atomicAdd.
__global__ __launch_bounds__(512, 4)
void k_gemm(const bf16* __restrict__ W2T, const float* __restrict__ gp,
            const float* __restrict__ G, const float* __restrict__ Wc1,
            const float* __restrict__ xf, const float* __restrict__ bc2,
            const float* __restrict__ Wc3, const float* __restrict__ bc3,
            float* __restrict__ fine) {
  __shared__ __align__(16) bf16 As[2][128 * 32];   // 2 x 8 KB
  __shared__ __align__(16) bf16 Bs[2][256 * 32];   // 2 x 16 KB
  __shared__ __align__(16) float Ps[8][512];       // 16 KB
  __shared__ float facc[128][3];                   // 1.5 KB
  const int t = threadIdx.x;
  const int mblk = blockIdx.x >> 1, nblk = blockIdx.x & 1;
  const int m0 = mblk * 128;
  const int w = t >> 6, l = t & 63, q = l >> 4, lm = l & 15;
  const int wm = (w >> 2) * 64;          // wave output-row base (0 or 64)
  const int wn = (w & 3) * 64;           // wave output-col base within N-half
  const int qs = (q ^ ((lm >> 1) & 3)) << 4;  // swizzled 16B slot for frag reads

  if (t < 384) ((float*)facc)[t] = 0.f;

  // ---- A-compute role: thread -> (row arow, k-subgroup cg of 8) ----
  const int arow = t >> 2, cg = t & 3;
  const int m = m0 + arow;
  const int b = m >> 14;                 // batch, uniform per block
  const int f = m & 16383;
  const int g = f & 15;
  const float* gr = G + (g << 9);                       // G row (512 f32)
  const float* pl = Ps[arow >> 4];                      // local P row in LDS
  char* awr = (char*)As + arow * 64 + ((cg ^ ((arow >> 1) & 3)) << 4); // + buf*8192

  // ---- P prologue: Ps[cl][k] = gp[b][k] + x·Wc1[2:5][k], 8 elems/thread ----
  {
    const int cl = t >> 6;               // local coarse point 0..7
    const int k8 = (t & 63) * 8;
    const int cglob = ((m0 & 16383) >> 4) + cl;
    const float* xq = xf + (b * 1024 + cglob) * 3;
    const float x0 = xq[0], x1 = xq[1], x2 = xq[2];
    const float* gpb = gp + (b << 9) + k8;
    float4 gv0 = *(const float4*)(gpb);
    float4 gv1 = *(const float4*)(gpb + 4);
    float4 w20 = *(const float4*)(Wc1 + 2 * 512 + k8);
    float4 w21 = *(const float4*)(Wc1 + 2 * 512 + k8 + 4);
    float4 w30 = *(const float4*)(Wc1 + 3 * 512 + k8);
    float4 w31 = *(const float4*)(Wc1 + 3 * 512 + k8 + 4);
    float4 w40 = *(const float4*)(Wc1 + 4 * 512 + k8);
    float4 w41 = *(const float4*)(Wc1 + 4 * 512 + k8 + 4);
    float4 r0, r1;
#pragma unroll
    for (int j = 0; j < 4; ++j) {
      ((float*)&r0)[j] = fmaf(x2, ((const float*)&w40)[j],
                         fmaf(x1, ((const float*)&w30)[j],
                         fmaf(x0, ((const float*)&w20)[j], ((const float*)&gv0)[j])));
      ((float*)&r1)[j] = fmaf(x2, ((const float*)&w41)[j],
                         fmaf(x1, ((const float*)&w31)[j],
                         fmaf(x0, ((const float*)&w21)[j], ((const float*)&gv1)[j])));
    }
    *(float4*)&Ps[cl][k8] = r0;
    *(float4*)&Ps[cl][k8 + 4] = r1;
  }

  // ---- B staging role: wave stages rows [w*32, w*32+32), 2 gload16/thread ----
  const char* bsrc = (const char*)W2T +
      (size_t)(nblk * 256 + w * 32 + (l >> 2)) * 1024 + (l & 3) * 16;
  char* bdst = (char*)Bs + w * 2048 + l * 16;      // + buf*16384 + i*1024

  v4f acc[4][4];
#pragma unroll
  for (int mi = 0; mi < 4; ++mi)
#pragma unroll
    for (int ni = 0; ni < 4; ++ni) acc[mi][ni] = (v4f){0.f, 0.f, 0.f, 0.f};

  // G prefetch registers (T14-on-G): hold G(kt+1) across phase kt
  float4 ga0, ga1;
  auto loadG = [&](int kt) {
    const int kk = kt * 32 + cg * 8;
    ga0 = *(const float4*)(gr + kk);
    ga1 = *(const float4*)(gr + kk + 4);
  };
  auto stage = [&](int kt, int buf) {
    // B: async loads in flight first
    const char* src = bsrc + kt * 64;
    char* dst = bdst + buf * 16384;
    gload16(src, dst);
    gload16(src + 16384, dst + 1024);    // +16 rows
    // A: relu(P + G); P broadcast ds_read, G from registers loaded LAST phase
    const int kk = kt * 32 + cg * 8;
    float4 p0 = *(const float4*)(pl + kk);
    float4 p1 = *(const float4*)(pl + kk + 4);
    union { bf16 h[8]; uint4 u; } o;
#pragma unroll
    for (int j = 0; j < 4; ++j) {
      o.h[j]     = tob(fmaxf(((const float*)&p0)[j] + ((const float*)&ga0)[j], 0.f));
      o.h[4 + j] = tob(fmaxf(((const float*)&p1)[j] + ((const float*)&ga1)[j], 0.f));
    }
    *(uint4*)(awr + buf * 8192) = o.u;
  };

  loadG(0);
  __syncthreads();                       // Ps visible to all waves
  stage(0, 0);
  loadG(1);                              // in flight across phase 0

#pragma unroll 2
  for (int kt = 0; kt < 16; ++kt) {
    const int buf = kt & 1;
    __syncthreads();                     // stage(kt,buf) complete on all waves
    if (kt < 15) {
      stage(kt + 1, buf ^ 1);            // consumes G(kt+1) prefetched regs
      if (kt < 14) loadG(kt + 2);        // issue AFTER gload16s: in-order vmcnt
    }
    const char* ab = (const char*)As + buf * 8192;
    const char* bb = (const char*)Bs + buf * 16384;
    v8s af[4], bfr[4];
#pragma unroll
    for (int mi = 0; mi < 4; ++mi)
      af[mi] = *(const v8s*)(ab + (wm + mi * 16 + lm) * 64 + qs);
#pragma unroll
    for (int ni = 0; ni < 4; ++ni)
      bfr[ni] = *(const v8s*)(bb + (wn + ni * 16 + lm) * 64 + qs);
#pragma unroll
    for (int mi = 0; mi < 4; ++mi)
#pragma unroll
      for (int ni = 0; ni < 4; ++ni)
        acc[mi][ni] = __builtin_amdgcn_mfma_f32_16x16x32_bf16(af[mi], bfr[ni], acc[mi][ni], 0, 0, 0);
  }

  // ---- epilogue: h2 = relu(acc + b_c2); fine partials via Wc3 ----
  float part[4][4][3];
#pragma unroll
  for (int mi = 0; mi < 4; ++mi)
#pragma unroll
    for (int r = 0; r < 4; ++r) { part[mi][r][0] = 0.f; part[mi][r][1] = 0.f; part[mi][r][2] = 0.f; }
#pragma unroll
  for (int ni = 0; ni < 4; ++ni) {
    const int n = nblk * 256 + wn + ni * 16 + lm;
    const float bv = bc2[n];
    const float w30 = Wc3[n * 3 + 0];
    const float w31 = Wc3[n * 3 + 1];
    const float w32 = Wc3[n * 3 + 2];
#pragma unroll
    for (int mi = 0; mi < 4; ++mi)
#pragma unroll
      for (int r = 0; r < 4; ++r) {
        float v = fmaxf(acc[mi][ni][r] + bv, 0.f);
        part[mi][r][0] = fmaf(v, w30, part[mi][r][0]);
        part[mi][r][1] = fmaf(v, w31, part[mi][r][1]);
        part[mi][r][2] = fmaf(v, w32, part[mi][r][2]);
      }
  }
#pragma unroll
  for (int mi = 0; mi < 4; ++mi)
#pragma unroll
    for (int r = 0; r < 4; ++r)
#pragma unroll
      for (int j = 0; j < 3; ++j) {
        float v = red16(part[mi][r][j]);   // DPP 16-lane sum (lm group)
        if (lm == 0) atomicAdd(&facc[wm + mi * 16 + q * 4 + r][j], v);
      }
  __syncthreads();
  if (t < 128) {
    const int mm = m0 + t;
    float* fp = fine + (size_t)mm * 3;
    float base[3] = {0.f, 0.f, 0.f};
    if (nblk == 0) {
      const int bb2 = mm >> 14, cc = (mm & 16383) >> 4;
      const float* xq = xf + (bb2 * 1024 + cc) * 3;
#pragma unroll
      for (int j = 0; j < 3; ++j) base[j] = bc3[j] + xq[j];
    }
#pragma unroll
    for (int j = 0; j < 3; ++j)
      atomicAdd(&fp[j], facc[t][j] + base[j]);
  }
}

extern "C" void kernel_launch(void* const* d_in, const int* in_sizes, int n_in,
                              void* d_out, int out_size, void* d_ws, size_t ws_size,
                              hipStream_t stream) {
  const float* fea = (const float*)d_in[0];
  const float* Wl1 = (const float*)d_in[1];
  const float* bl1 = (const float*)d_in[2];
  const float* Wl2 = (const float*)d_in[3];
  const float* bl2 = (const float*)d_in[4];
  const float* Wc1 = (const float*)d_in[5];
  const float* bc1 = (const float*)d_in[6];
  const float* Wc2 = (const float*)d_in[7];
  const float* bc2 = (const float*)d_in[8];
  const float* Wc3 = (const float*)d_in[9];
  const float* bc3 = (const float*)d_in[10];
  float* xout = (float*)d_out;                // (8,1024,3)
  float* fine = (float*)d_out + 24576;        // (8,16384,3)
  char* ws = (char*)d_ws;
  float* h1  = (float*)ws;                    // 32 KB
  float* xf  = (float*)(ws + 32768);          // 96 KB
  float* gp  = (float*)(ws + 131072);         // 16 KB
  bf16*  W2T = (bf16*)(ws + 147456);          // 512 KB
  float* G   = (float*)(ws + 671744);         // 32 KB

  k_pre<<<1409, 256, 0, stream>>>(fea, Wl1, bl1, Wc1, bc1, Wc2, h1, gp, W2T, G, fine);
  k_lin2<<<1536, 256, 0, stream>>>(h1, Wl2, bl2, xf, xout);
  k_gemm<<<2048, 512, 0, stream>>>(W2T, gp, G, Wc1, xf, bc2, Wc3, bc3, fine);
}

// Round 11
// 174.375 us; speedup vs baseline: 1.4451x; 1.0369x over previous
//
#include <hip/hip_runtime.h>
#include <hip/hip_bf16.h>
#include <stdint.h>

typedef __hip_bfloat16 bf16;
typedef __attribute__((ext_vector_type(8))) short v8s;   // 8 bf16 in 4 VGPRs
typedef __attribute__((ext_vector_type(4))) float v4f;   // MFMA C/D frag

__device__ __forceinline__ bf16 tob(float x) { return __float2bfloat16(x); }

// async global->LDS, 16B per lane; LDS dest must be wave-uniform base + lane*16
__device__ __forceinline__ void gload16(const void* g, void* l) {
  __builtin_amdgcn_global_load_lds(
      (const __attribute__((address_space(1))) uint32_t*)g,
      (__attribute__((address_space(3))) uint32_t*)l,
      16, 0, 0);
}

// Sum over each aligned 16-lane group via DPP (VALU pipe, no LDS crossbar).
__device__ __forceinline__ float red16(float v) {
  v += __int_as_float(__builtin_amdgcn_update_dpp(0, __float_as_int(v), 0xB1, 0xF, 0xF, true));
  v += __int_as_float(__builtin_amdgcn_update_dpp(0, __float_as_int(v), 0x4E, 0xF, 0xF, true));
  v += __int_as_float(__builtin_amdgcn_update_dpp(0, __float_as_int(v), 0x141, 0xF, 0xF, true));
  v += __int_as_float(__builtin_amdgcn_update_dpp(0, __float_as_int(v), 0x140, 0xF, 0xF, true));
  return v;
}

// ============ fused input-only preprocessing (1 launch) ============
// blocks 0..511    : h1 = relu(fea @ W_l1 + b_l1)         (8,1024), K=1024
// blocks 512..767  : gp[b,n] = fea[b] @ W_c1[5:,n] + bc1  (8,512),  K=1024
// blocks 768..1023 : W2T[n,k-swz] = bf16(W_c2[k,n])       (512,512), pre-swizzled
// block  1024      : G[g,k] = gx*Wc1[0,k] + gy*Wc1[1,k]   (16,512)
// blocks 1025..1408: fine = 0
__global__ void k_pre(const float* __restrict__ fea, const float* __restrict__ Wl1,
                      const float* __restrict__ bl1, const float* __restrict__ Wc1,
                      const float* __restrict__ bc1, const float* __restrict__ Wc2,
                      float* __restrict__ h1, float* __restrict__ gp,
                      bf16* __restrict__ WT, float* __restrict__ G,
                      float* __restrict__ fine) {
  __shared__ __align__(16) float sm[32 * 33 + 32];
  const int bid = blockIdx.x;
  if (bid < 512) {                     // ---- lin1 ----
    float* red = sm;
    const int nl = threadIdx.x & 15, ks = threadIdx.x >> 4;
    const int o = bid * 16 + nl;
    const int b = o >> 10, n = o & 1023;
    const float* fr = fea + (b << 10) + ks * 64;
    const float* wp = Wl1 + (size_t)(ks * 64) * 1024 + n;
    float acc = 0.f;
#pragma unroll 8
    for (int j = 0; j < 64; ++j)
      acc = fmaf(fr[j], wp[(size_t)j * 1024], acc);
    red[threadIdx.x] = acc;
    __syncthreads();
    if (threadIdx.x < 16) {
      float s = bl1[n];
#pragma unroll
      for (int i = 0; i < 16; ++i) s += red[i * 16 + threadIdx.x];
      h1[o] = fmaxf(s, 0.f);
    }
  } else if (bid < 768) {              // ---- gp ----
    float* red = sm;
    const int nl = threadIdx.x & 15, ks = threadIdx.x >> 4;
    const int o = (bid - 512) * 16 + nl;
    const int b = o >> 9, n = o & 511;
    const float* fr = fea + (b << 10) + ks * 64;
    const float* wp = Wc1 + (size_t)(5 + ks * 64) * 512 + n;
    float acc = 0.f;
#pragma unroll 8
    for (int j = 0; j < 64; ++j)
      acc = fmaf(fr[j], wp[(size_t)j * 512], acc);
    red[threadIdx.x] = acc;
    __syncthreads();
    if (threadIdx.x < 16) {
      float s = bc1[n];
#pragma unroll
      for (int i = 0; i < 16; ++i) s += red[i * 16 + threadIdx.x];
      gp[o] = s;
    }
  } else if (bid < 1024) {             // ---- w2t (pre-swizzled transpose) ----
    float (*tile)[33] = (float(*)[33])sm;
    const int bb = bid - 768;
    int bx = bb & 15, by = bb >> 4;
    int c = threadIdx.x & 31, r8 = threadIdx.x >> 5;
#pragma unroll
    for (int i = 0; i < 4; ++i) {
      int r = r8 + i * 8;
      tile[r][c] = Wc2[(by * 32 + r) * 512 + bx * 32 + c];
    }
    __syncthreads();
#pragma unroll
    for (int i = 0; i < 4; ++i) {
      int r = r8 + i * 8;
      int n = bx * 32 + r;                       // output row (conv2 in-chan)
      int k = by * 32 + c;                       // original k
      int s = (c >> 3) & 3;                      // 16B slot in 64B K-block
      int ks = (k & ~24) | (((s ^ ((n >> 1) & 3)) & 3) << 3);
      WT[(size_t)n * 512 + ks] = tob(tile[c][r]);
    }
  } else if (bid == 1024) {            // ---- grid table ----
    for (int e = threadIdx.x; e < 8192; e += 256) {
      int g = e >> 9, k = e & 511;
      const float gx = -0.05f + (float)(g & 3) * (0.1f / 3.0f);
      const float gy = -0.05f + (float)(g >> 2) * (0.1f / 3.0f);
      G[e] = fmaf(gy, Wc1[512 + k], gx * Wc1[k]);
    }
  } else {                             // ---- zero fine (393216 floats) ----
    const int i = ((bid - 1025) * 256 + threadIdx.x) * 4;
    *(float4*)(fine + i) = (float4){0.f, 0.f, 0.f, 0.f};
  }
}

// x = h1 @ W_l2 + b_l2   (8,3072), K=1024 -> xf (ws) + xout (d_out)
// Round-10 version (verified correct: Output 0 passed). One block per 16-n
// group, FULL K=1024 in block (no cross-block combine -> no round-9 race).
// W_l2 read exactly once (12.6 MB; round-8 layout read it 8x). h1 (32 KB) in
// LDS, broadcast. 192 blocks x 256 threads.
__global__ void k_lin2(const float* __restrict__ h1, const float* __restrict__ W,
                       const float* __restrict__ bias, float* __restrict__ xf,
                       float* __restrict__ xout) {
  __shared__ float h1s[8][1024];         // 32 KB
  __shared__ float red[16][16][9];       // 9 KB [ks][nl][b], pad 9: bank spread
  const int t = threadIdx.x;             // 256
  const int n0 = blockIdx.x * 16;        // 192 blocks
  for (int i = t; i < 8192; i += 256)    // h1 is (8,1024) contiguous
    ((float*)h1s)[i] = h1[i];
  __syncthreads();
  const int nl = t & 15, ks = t >> 4;
  const int n = n0 + nl;
  float acc[8] = {0.f, 0.f, 0.f, 0.f, 0.f, 0.f, 0.f, 0.f};
  const float* wp = W + (size_t)(ks * 64) * 3072 + n;
#pragma unroll 8
  for (int j = 0; j < 64; ++j) {
    float wv = wp[(size_t)j * 3072];
    const float* hk = &h1s[0][ks * 64 + j];
#pragma unroll
    for (int b = 0; b < 8; ++b) acc[b] = fmaf(hk[b * 1024], wv, acc[b]);
  }
#pragma unroll
  for (int b = 0; b < 8; ++b) red[ks][nl][b] = acc[b];
  __syncthreads();
  if (t < 128) {                         // 128 outputs: (nn, b)
    const int nn = t & 15, b = t >> 4;
    float s = bias[n0 + nn];
#pragma unroll
    for (int i = 0; i < 16; ++i) s += red[i][nn][b];
    const int o = b * 3072 + n0 + nn;
    xf[o] = s;
    xout[o] = s;
  }
}

// ============ fused conv1+conv2 GEMM + conv3 epilogue ============
// BYTE-EXACT round-8 k_gemm (last passing version, 91 us).
// ROUND-10 LESSON: the round-9 "frag-reads-before-stage" reorder -- analyzed
// three times as a semantic no-op -- produced 2.3e35 garbage in fine. The
// barrier/buffer analysis says no race, which means the failure lives in the
// compiler's scheduling of the hoisted ds_reads against the async
// global_load_lds issue (the DMA's LDS-write is not modeled as a DS op).
// DO NOT reorder frag reads ahead of stage() in this structure.
// Structure: 2048 blocks x 512 thr; rows m0..m0+127, N-half nblk*256..+255,
// K=512, BK=32; LDS 67072 -> 2 blocks/CU. P in LDS (Ps prologue); G reg-
// prefetched one phase ahead (neutral but harmless); B via gload16 from
// pre-swizzled W2T; A k-slot swizzle (row>>1)&3 write+read (conflict-free).
// LAUNCH-BOUNDS RULE (measured twice): (512,6) truncates VGPR below demand ->
// scratch-spill disaster (rounds 1 & 4). Keep (512,4).
// Epilogue conv3: DPP 16-lane reduce -> facc -> global atomicAdd.
__global__ __launch_bounds__(512, 4)
void k_gemm(const bf16* __restrict__ W2T, const float* __restrict__ gp,
            const float* __restrict__ G, const float* __restrict__ Wc1,
            const float* __restrict__ xf, const float* __restrict__ bc2,
            const float* __restrict__ Wc3, const float* __restrict__ bc3,
            float* __restrict__ fine) {
  __shared__ __align__(16) bf16 As[2][128 * 32];   // 2 x 8 KB
  __shared__ __align__(16) bf16 Bs[2][256 * 32];   // 2 x 16 KB
  __shared__ __align__(16) float Ps[8][512];       // 16 KB
  __shared__ float facc[128][3];                   // 1.5 KB
  const int t = threadIdx.x;
  const int mblk = blockIdx.x >> 1, nblk = blockIdx.x & 1;
  const int m0 = mblk * 128;
  const int w = t >> 6, l = t & 63, q = l >> 4, lm = l & 15;
  const int wm = (w >> 2) * 64;          // wave output-row base (0 or 64)
  const int wn = (w & 3) * 64;           // wave output-col base within N-half
  const int qs = (q ^ ((lm >> 1) & 3)) << 4;  // swizzled 16B slot for frag reads

  if (t < 384) ((float*)facc)[t] = 0.f;

  // ---- A-compute role: thread -> (row arow, k-subgroup cg of 8) ----
  const int arow = t >> 2, cg = t & 3;
  const int m = m0 + arow;
  const int b = m >> 14;                 // batch, uniform per block
  const int f = m & 16383;
  const int g = f & 15;
  const float* gr = G + (g << 9);                       // G row (512 f32)
  const float* pl = Ps[arow >> 4];                      // local P row in LDS
  char* awr = (char*)As + arow * 64 + ((cg ^ ((arow >> 1) & 3)) << 4); // + buf*8192

  // ---- P prologue: Ps[cl][k] = gp[b][k] + x·Wc1[2:5][k], 8 elems/thread ----
  {
    const int cl = t >> 6;               // local coarse point 0..7
    const int k8 = (t & 63) * 8;
    const int cglob = ((m0 & 16383) >> 4) + cl;
    const float* xq = xf + (b * 1024 + cglob) * 3;
    const float x0 = xq[0], x1 = xq[1], x2 = xq[2];
    const float* gpb = gp + (b << 9) + k8;
    float4 gv0 = *(const float4*)(gpb);
    float4 gv1 = *(const float4*)(gpb + 4);
    float4 w20 = *(const float4*)(Wc1 + 2 * 512 + k8);
    float4 w21 = *(const float4*)(Wc1 + 2 * 512 + k8 + 4);
    float4 w30 = *(const float4*)(Wc1 + 3 * 512 + k8);
    float4 w31 = *(const float4*)(Wc1 + 3 * 512 + k8 + 4);
    float4 w40 = *(const float4*)(Wc1 + 4 * 512 + k8);
    float4 w41 = *(const float4*)(Wc1 + 4 * 512 + k8 + 4);
    float4 r0, r1;
#pragma unroll
    for (int j = 0; j < 4; ++j) {
      ((float*)&r0)[j] = fmaf(x2, ((const float*)&w40)[j],
                         fmaf(x1, ((const float*)&w30)[j],
                         fmaf(x0, ((const float*)&w20)[j], ((const float*)&gv0)[j])));
      ((float*)&r1)[j] = fmaf(x2, ((const float*)&w41)[j],
                         fmaf(x1, ((const float*)&w31)[j],
                         fmaf(x0, ((const float*)&w21)[j], ((const float*)&gv1)[j])));
    }
    *(float4*)&Ps[cl][k8] = r0;
    *(float4*)&Ps[cl][k8 + 4] = r1;
  }

  // ---- B staging role: wave stages rows [w*32, w*32+32), 2 gload16/thread ----
  const char* bsrc = (const char*)W2T +
      (size_t)(nblk * 256 + w * 32 + (l >> 2)) * 1024 + (l & 3) * 16;
  char* bdst = (char*)Bs + w * 2048 + l * 16;      // + buf*16384 + i*1024

  v4f acc[4][4];
#pragma unroll
  for (int mi = 0; mi < 4; ++mi)
#pragma unroll
    for (int ni = 0; ni < 4; ++ni) acc[mi][ni] = (v4f){0.f, 0.f, 0.f, 0.f};

  // G prefetch registers: hold G(kt+1) across phase kt (neutral, kept from r8)
  float4 ga0, ga1;
  auto loadG = [&](int kt) {
    const int kk = kt * 32 + cg * 8;
    ga0 = *(const float4*)(gr + kk);
    ga1 = *(const float4*)(gr + kk + 4);
  };
  auto stage = [&](int kt, int buf) {
    // B: async loads in flight first
    const char* src = bsrc + kt * 64;
    char* dst = bdst + buf * 16384;
    gload16(src, dst);
    gload16(src + 16384, dst + 1024);    // +16 rows
    // A: relu(P + G); P broadcast ds_read, G from registers loaded LAST phase
    const int kk = kt * 32 + cg * 8;
    float4 p0 = *(const float4*)(pl + kk);
    float4 p1 = *(const float4*)(pl + kk + 4);
    union { bf16 h[8]; uint4 u; } o;
#pragma unroll
    for (int j = 0; j < 4; ++j) {
      o.h[j]     = tob(fmaxf(((const float*)&p0)[j] + ((const float*)&ga0)[j], 0.f));
      o.h[4 + j] = tob(fmaxf(((const float*)&p1)[j] + ((const float*)&ga1)[j], 0.f));
    }
    *(uint4*)(awr + buf * 8192) = o.u;
  };

  loadG(0);
  __syncthreads();                       // Ps visible to all waves
  stage(0, 0);
  loadG(1);                              // in flight across phase 0

#pragma unroll 2
  for (int kt = 0; kt < 16; ++kt) {
    const int buf = kt & 1;
    __syncthreads();                     // stage(kt,buf) complete on all waves
    if (kt < 15) {
      stage(kt + 1, buf ^ 1);            // consumes G(kt+1) prefetched regs
      if (kt < 14) loadG(kt + 2);        // issue AFTER gload16s: in-order vmcnt
    }
    const char* ab = (const char*)As + buf * 8192;
    const char* bb = (const char*)Bs + buf * 16384;
    v8s af[4], bfr[4];
#pragma unroll
    for (int mi = 0; mi < 4; ++mi)
      af[mi] = *(const v8s*)(ab + (wm + mi * 16 + lm) * 64 + qs);
#pragma unroll
    for (int ni = 0; ni < 4; ++ni)
      bfr[ni] = *(const v8s*)(bb + (wn + ni * 16 + lm) * 64 + qs);
#pragma unroll
    for (int mi = 0; mi < 4; ++mi)
#pragma unroll
      for (int ni = 0; ni < 4; ++ni)
        acc[mi][ni] = __builtin_amdgcn_mfma_f32_16x16x32_bf16(af[mi], bfr[ni], acc[mi][ni], 0, 0, 0);
  }

  // ---- epilogue: h2 = relu(acc + b_c2); fine partials via Wc3 ----
  float part[4][4][3];
#pragma unroll
  for (int mi = 0; mi < 4; ++mi)
#pragma unroll
    for (int r = 0; r < 4; ++r) { part[mi][r][0] = 0.f; part[mi][r][1] = 0.f; part[mi][r][2] = 0.f; }
#pragma unroll
  for (int ni = 0; ni < 4; ++ni) {
    const int n = nblk * 256 + wn + ni * 16 + lm;
    const float bv = bc2[n];
    const float w30 = Wc3[n * 3 + 0];
    const float w31 = Wc3[n * 3 + 1];
    const float w32 = Wc3[n * 3 + 2];
#pragma unroll
    for (int mi = 0; mi < 4; ++mi)
#pragma unroll
      for (int r = 0; r < 4; ++r) {
        float v = fmaxf(acc[mi][ni][r] + bv, 0.f);
        part[mi][r][0] = fmaf(v, w30, part[mi][r][0]);
        part[mi][r][1] = fmaf(v, w31, part[mi][r][1]);
        part[mi][r][2] = fmaf(v, w32, part[mi][r][2]);
      }
  }
#pragma unroll
  for (int mi = 0; mi < 4; ++mi)
#pragma unroll
    for (int r = 0; r < 4; ++r)
#pragma unroll
      for (int j = 0; j < 3; ++j) {
        float v = red16(part[mi][r][j]);   // DPP 16-lane sum (lm group)
        if (lm == 0) atomicAdd(&facc[wm + mi * 16 + q * 4 + r][j], v);
      }
  __syncthreads();
  if (t < 128) {
    const int mm = m0 + t;
    float* fp = fine + (size_t)mm * 3;
    float base[3] = {0.f, 0.f, 0.f};
    if (nblk == 0) {
      const int bb2 = mm >> 14, cc = (mm & 16383) >> 4;
      const float* xq = xf + (bb2 * 1024 + cc) * 3;
#pragma unroll
      for (int j = 0; j < 3; ++j) base[j] = bc3[j] + xq[j];
    }
#pragma unroll
    for (int j = 0; j < 3; ++j)
      atomicAdd(&fp[j], facc[t][j] + base[j]);
  }
}

extern "C" void kernel_launch(void* const* d_in, const int* in_sizes, int n_in,
                              void* d_out, int out_size, void* d_ws, size_t ws_size,
                              hipStream_t stream) {
  const float* fea = (const float*)d_in[0];
  const float* Wl1 = (const float*)d_in[1];
  const float* bl1 = (const float*)d_in[2];
  const float* Wl2 = (const float*)d_in[3];
  const float* bl2 = (const float*)d_in[4];
  const float* Wc1 = (const float*)d_in[5];
  const float* bc1 = (const float*)d_in[6];
  const float* Wc2 = (const float*)d_in[7];
  const float* bc2 = (const float*)d_in[8];
  const float* Wc3 = (const float*)d_in[9];
  const float* bc3 = (const float*)d_in[10];
  float* xout = (float*)d_out;                // (8,1024,3)
  float* fine = (float*)d_out + 24576;        // (8,16384,3)
  char* ws = (char*)d_ws;
  float* h1  = (float*)ws;                    // 32 KB
  float* xf  = (float*)(ws + 32768);          // 96 KB
  float* gp  = (float*)(ws + 131072);         // 16 KB
  bf16*  W2T = (bf16*)(ws + 147456);          // 512 KB
  float* G   = (float*)(ws + 671744);         // 32 KB

  k_pre<<<1409, 256, 0, stream>>>(fea, Wl1, bl1, Wc1, bc1, Wc2, h1, gp, W2T, G, fine);
  k_lin2<<<192, 256, 0, stream>>>(h1, Wl2, bl2, xf, xout);
  k_gemm<<<2048, 512, 0, stream>>>(W2T, gp, G, Wc1, xf, bc2, Wc3, bc3, fine);
}

// Round 12
// 173.537 us; speedup vs baseline: 1.4521x; 1.0048x over previous
//
#include <hip/hip_runtime.h>
#include <hip/hip_bf16.h>
#include <stdint.h>

typedef __hip_bfloat16 bf16;
typedef __attribute__((ext_vector_type(8))) short v8s;   // 8 bf16 in 4 VGPRs
typedef __attribute__((ext_vector_type(4))) float v4f;   // MFMA C/D frag

__device__ __forceinline__ bf16 tob(float x) { return __float2bfloat16(x); }

// async global->LDS, 16B per lane; LDS dest must be wave-uniform base + lane*16
__device__ __forceinline__ void gload16(const void* g, void* l) {
  __builtin_amdgcn_global_load_lds(
      (const __attribute__((address_space(1))) uint32_t*)g,
      (__attribute__((address_space(3))) uint32_t*)l,
      16, 0, 0);
}

// Sum over each aligned 16-lane group via DPP (VALU pipe, no LDS crossbar).
__device__ __forceinline__ float red16(float v) {
  v += __int_as_float(__builtin_amdgcn_update_dpp(0, __float_as_int(v), 0xB1, 0xF, 0xF, true));
  v += __int_as_float(__builtin_amdgcn_update_dpp(0, __float_as_int(v), 0x4E, 0xF, 0xF, true));
  v += __int_as_float(__builtin_amdgcn_update_dpp(0, __float_as_int(v), 0x141, 0xF, 0xF, true));
  v += __int_as_float(__builtin_amdgcn_update_dpp(0, __float_as_int(v), 0x140, 0xF, 0xF, true));
  return v;
}

// ============ fused input-only preprocessing (1 launch) ============
// blocks 0..511    : h1 = relu(fea @ W_l1 + b_l1)         (8,1024), K=1024
// blocks 512..767  : gp[b,n] = fea[b] @ W_c1[5:,n] + bc1  (8,512),  K=1024
// blocks 768..1023 : W2T[n,k-swz] = bf16(W_c2[k,n])       (512,512), pre-swizzled
// block  1024      : G[g,k] = gx*Wc1[0,k] + gy*Wc1[1,k]   (16,512)
// blocks 1025..1408: fine = 0
__global__ void k_pre(const float* __restrict__ fea, const float* __restrict__ Wl1,
                      const float* __restrict__ bl1, const float* __restrict__ Wc1,
                      const float* __restrict__ bc1, const float* __restrict__ Wc2,
                      float* __restrict__ h1, float* __restrict__ gp,
                      bf16* __restrict__ WT, float* __restrict__ G,
                      float* __restrict__ fine) {
  __shared__ __align__(16) float sm[32 * 33 + 32];
  const int bid = blockIdx.x;
  if (bid < 512) {                     // ---- lin1 ----
    float* red = sm;
    const int nl = threadIdx.x & 15, ks = threadIdx.x >> 4;
    const int o = bid * 16 + nl;
    const int b = o >> 10, n = o & 1023;
    const float* fr = fea + (b << 10) + ks * 64;
    const float* wp = Wl1 + (size_t)(ks * 64) * 1024 + n;
    float acc = 0.f;
#pragma unroll 8
    for (int j = 0; j < 64; ++j)
      acc = fmaf(fr[j], wp[(size_t)j * 1024], acc);
    red[threadIdx.x] = acc;
    __syncthreads();
    if (threadIdx.x < 16) {
      float s = bl1[n];
#pragma unroll
      for (int i = 0; i < 16; ++i) s += red[i * 16 + threadIdx.x];
      h1[o] = fmaxf(s, 0.f);
    }
  } else if (bid < 768) {              // ---- gp ----
    float* red = sm;
    const int nl = threadIdx.x & 15, ks = threadIdx.x >> 4;
    const int o = (bid - 512) * 16 + nl;
    const int b = o >> 9, n = o & 511;
    const float* fr = fea + (b << 10) + ks * 64;
    const float* wp = Wc1 + (size_t)(5 + ks * 64) * 512 + n;
    float acc = 0.f;
#pragma unroll 8
    for (int j = 0; j < 64; ++j)
      acc = fmaf(fr[j], wp[(size_t)j * 512], acc);
    red[threadIdx.x] = acc;
    __syncthreads();
    if (threadIdx.x < 16) {
      float s = bc1[n];
#pragma unroll
      for (int i = 0; i < 16; ++i) s += red[i * 16 + threadIdx.x];
      gp[o] = s;
    }
  } else if (bid < 1024) {             // ---- w2t (pre-swizzled transpose) ----
    float (*tile)[33] = (float(*)[33])sm;
    const int bb = bid - 768;
    int bx = bb & 15, by = bb >> 4;
    int c = threadIdx.x & 31, r8 = threadIdx.x >> 5;
#pragma unroll
    for (int i = 0; i < 4; ++i) {
      int r = r8 + i * 8;
      tile[r][c] = Wc2[(by * 32 + r) * 512 + bx * 32 + c];
    }
    __syncthreads();
#pragma unroll
    for (int i = 0; i < 4; ++i) {
      int r = r8 + i * 8;
      int n = bx * 32 + r;                       // output row (conv2 in-chan)
      int k = by * 32 + c;                       // original k
      int s = (c >> 3) & 3;                      // 16B slot in 64B K-block
      int ks = (k & ~24) | (((s ^ ((n >> 1) & 3)) & 3) << 3);
      WT[(size_t)n * 512 + ks] = tob(tile[c][r]);
    }
  } else if (bid == 1024) {            // ---- grid table ----
    for (int e = threadIdx.x; e < 8192; e += 256) {
      int g = e >> 9, k = e & 511;
      const float gx = -0.05f + (float)(g & 3) * (0.1f / 3.0f);
      const float gy = -0.05f + (float)(g >> 2) * (0.1f / 3.0f);
      G[e] = fmaf(gy, Wc1[512 + k], gx * Wc1[k]);
    }
  } else {                             // ---- zero fine (393216 floats) ----
    const int i = ((bid - 1025) * 256 + threadIdx.x) * 4;
    *(float4*)(fine + i) = (float4){0.f, 0.f, 0.f, 0.f};
  }
}

// x = h1 @ W_l2 + b_l2   (8,3072), K=1024 -> xf (ws) + xout (d_out)
// One block per 16-n group, FULL K=1024 in block (no cross-block combine).
// W_l2 read exactly once. h1 (32 KB) in LDS, broadcast. 192 blocks x 256 thr.
__global__ void k_lin2(const float* __restrict__ h1, const float* __restrict__ W,
                       const float* __restrict__ bias, float* __restrict__ xf,
                       float* __restrict__ xout) {
  __shared__ float h1s[8][1024];         // 32 KB
  __shared__ float red[16][16][9];       // 9 KB [ks][nl][b], pad 9: bank spread
  const int t = threadIdx.x;             // 256
  const int n0 = blockIdx.x * 16;        // 192 blocks
  for (int i = t; i < 8192; i += 256)    // h1 is (8,1024) contiguous
    ((float*)h1s)[i] = h1[i];
  __syncthreads();
  const int nl = t & 15, ks = t >> 4;
  const int n = n0 + nl;
  float acc[8] = {0.f, 0.f, 0.f, 0.f, 0.f, 0.f, 0.f, 0.f};
  const float* wp = W + (size_t)(ks * 64) * 3072 + n;
#pragma unroll 8
  for (int j = 0; j < 64; ++j) {
    float wv = wp[(size_t)j * 3072];
    const float* hk = &h1s[0][ks * 64 + j];
#pragma unroll
    for (int b = 0; b < 8; ++b) acc[b] = fmaf(hk[b * 1024], wv, acc[b]);
  }
#pragma unroll
  for (int b = 0; b < 8; ++b) red[ks][nl][b] = acc[b];
  __syncthreads();
  if (t < 128) {                         // 128 outputs: (nn, b)
    const int nn = t & 15, b = t >> 4;
    float s = bias[n0 + nn];
#pragma unroll
    for (int i = 0; i < 16; ++i) s += red[i][nn][b];
    const int o = b * 3072 + n0 + nn;
    xf[o] = s;
    xout[o] = s;
  }
}

// ============ fused conv1+conv2 GEMM + conv3 epilogue ============
// Round-11 k_gemm (passing, 90.6 us) with ONE change: contention-free epilogue.
// Pipe model (corrected: VALUBusy includes MFMA issue -> scalar-VALU ~13%,
// MFMA 31%, LDS ~60-62% = dominant pipe). The epilogue's 192 LDS atomicAdds
// per wave into facc were 4-way contended RMW across the simultaneous n-waves.
// NEW: facc4[4][128][3], slice per n-wave (w&3) -> every (slice,row,j) written
// by exactly one lane once -> plain ds_write, no atomics, no zero-init; final
// t<128 readout sums the 4 slices. Numerically identical (fixed sum order).
// No barrier/async/gload16 ordering touched (the r9/r10 failure class).
// ROUND-10 LESSON: do NOT reorder frag reads ahead of stage() (compiler
// scheduling of ds_reads vs global_load_lds issue broke correctness).
// LAUNCH-BOUNDS RULE (measured twice): (512,6) truncates VGPR below demand ->
// scratch-spill disaster (rounds 1 & 4). Keep (512,4).
// Structure: 2048 blocks x 512 thr; rows m0..m0+127, N-half nblk*256..+255,
// K=512, BK=32; LDS 71680 -> 2 blocks/CU. P in LDS (Ps prologue); G reg-
// prefetched one phase ahead; B via gload16 from pre-swizzled W2T; A k-slot
// swizzle (row>>1)&3 write+read (conflict-free).
__global__ __launch_bounds__(512, 4)
void k_gemm(const bf16* __restrict__ W2T, const float* __restrict__ gp,
            const float* __restrict__ G, const float* __restrict__ Wc1,
            const float* __restrict__ xf, const float* __restrict__ bc2,
            const float* __restrict__ Wc3, const float* __restrict__ bc3,
            float* __restrict__ fine) {
  __shared__ __align__(16) bf16 As[2][128 * 32];   // 2 x 8 KB
  __shared__ __align__(16) bf16 Bs[2][256 * 32];   // 2 x 16 KB
  __shared__ __align__(16) float Ps[8][512];       // 16 KB
  __shared__ float facc4[4][128][3];               // 6 KB, slice per n-wave
  const int t = threadIdx.x;
  const int mblk = blockIdx.x >> 1, nblk = blockIdx.x & 1;
  const int m0 = mblk * 128;
  const int w = t >> 6, l = t & 63, q = l >> 4, lm = l & 15;
  const int wm = (w >> 2) * 64;          // wave output-row base (0 or 64)
  const int wn = (w & 3) * 64;           // wave output-col base within N-half
  const int qs = (q ^ ((lm >> 1) & 3)) << 4;  // swizzled 16B slot for frag reads

  // ---- A-compute role: thread -> (row arow, k-subgroup cg of 8) ----
  const int arow = t >> 2, cg = t & 3;
  const int m = m0 + arow;
  const int b = m >> 14;                 // batch, uniform per block
  const int f = m & 16383;
  const int g = f & 15;
  const float* gr = G + (g << 9);                       // G row (512 f32)
  const float* pl = Ps[arow >> 4];                      // local P row in LDS
  char* awr = (char*)As + arow * 64 + ((cg ^ ((arow >> 1) & 3)) << 4); // + buf*8192

  // ---- P prologue: Ps[cl][k] = gp[b][k] + x·Wc1[2:5][k], 8 elems/thread ----
  {
    const int cl = t >> 6;               // local coarse point 0..7
    const int k8 = (t & 63) * 8;
    const int cglob = ((m0 & 16383) >> 4) + cl;
    const float* xq = xf + (b * 1024 + cglob) * 3;
    const float x0 = xq[0], x1 = xq[1], x2 = xq[2];
    const float* gpb = gp + (b << 9) + k8;
    float4 gv0 = *(const float4*)(gpb);
    float4 gv1 = *(const float4*)(gpb + 4);
    float4 w20 = *(const float4*)(Wc1 + 2 * 512 + k8);
    float4 w21 = *(const float4*)(Wc1 + 2 * 512 + k8 + 4);
    float4 w30 = *(const float4*)(Wc1 + 3 * 512 + k8);
    float4 w31 = *(const float4*)(Wc1 + 3 * 512 + k8 + 4);
    float4 w40 = *(const float4*)(Wc1 + 4 * 512 + k8);
    float4 w41 = *(const float4*)(Wc1 + 4 * 512 + k8 + 4);
    float4 r0, r1;
#pragma unroll
    for (int j = 0; j < 4; ++j) {
      ((float*)&r0)[j] = fmaf(x2, ((const float*)&w40)[j],
                         fmaf(x1, ((const float*)&w30)[j],
                         fmaf(x0, ((const float*)&w20)[j], ((const float*)&gv0)[j])));
      ((float*)&r1)[j] = fmaf(x2, ((const float*)&w41)[j],
                         fmaf(x1, ((const float*)&w31)[j],
                         fmaf(x0, ((const float*)&w21)[j], ((const float*)&gv1)[j])));
    }
    *(float4*)&Ps[cl][k8] = r0;
    *(float4*)&Ps[cl][k8 + 4] = r1;
  }

  // ---- B staging role: wave stages rows [w*32, w*32+32), 2 gload16/thread ----
  const char* bsrc = (const char*)W2T +
      (size_t)(nblk * 256 + w * 32 + (l >> 2)) * 1024 + (l & 3) * 16;
  char* bdst = (char*)Bs + w * 2048 + l * 16;      // + buf*16384 + i*1024

  v4f acc[4][4];
#pragma unroll
  for (int mi = 0; mi < 4; ++mi)
#pragma unroll
    for (int ni = 0; ni < 4; ++ni) acc[mi][ni] = (v4f){0.f, 0.f, 0.f, 0.f};

  // G prefetch registers: hold G(kt+1) across phase kt (neutral, kept from r8)
  float4 ga0, ga1;
  auto loadG = [&](int kt) {
    const int kk = kt * 32 + cg * 8;
    ga0 = *(const float4*)(gr + kk);
    ga1 = *(const float4*)(gr + kk + 4);
  };
  auto stage = [&](int kt, int buf) {
    // B: async loads in flight first
    const char* src = bsrc + kt * 64;
    char* dst = bdst + buf * 16384;
    gload16(src, dst);
    gload16(src + 16384, dst + 1024);    // +16 rows
    // A: relu(P + G); P broadcast ds_read, G from registers loaded LAST phase
    const int kk = kt * 32 + cg * 8;
    float4 p0 = *(const float4*)(pl + kk);
    float4 p1 = *(const float4*)(pl + kk + 4);
    union { bf16 h[8]; uint4 u; } o;
#pragma unroll
    for (int j = 0; j < 4; ++j) {
      o.h[j]     = tob(fmaxf(((const float*)&p0)[j] + ((const float*)&ga0)[j], 0.f));
      o.h[4 + j] = tob(fmaxf(((const float*)&p1)[j] + ((const float*)&ga1)[j], 0.f));
    }
    *(uint4*)(awr + buf * 8192) = o.u;
  };

  loadG(0);
  __syncthreads();                       // Ps visible to all waves
  stage(0, 0);
  loadG(1);                              // in flight across phase 0

#pragma unroll 2
  for (int kt = 0; kt < 16; ++kt) {
    const int buf = kt & 1;
    __syncthreads();                     // stage(kt,buf) complete on all waves
    if (kt < 15) {
      stage(kt + 1, buf ^ 1);            // consumes G(kt+1) prefetched regs
      if (kt < 14) loadG(kt + 2);        // issue AFTER gload16s: in-order vmcnt
    }
    const char* ab = (const char*)As + buf * 8192;
    const char* bb = (const char*)Bs + buf * 16384;
    v8s af[4], bfr[4];
#pragma unroll
    for (int mi = 0; mi < 4; ++mi)
      af[mi] = *(const v8s*)(ab + (wm + mi * 16 + lm) * 64 + qs);
#pragma unroll
    for (int ni = 0; ni < 4; ++ni)
      bfr[ni] = *(const v8s*)(bb + (wn + ni * 16 + lm) * 64 + qs);
#pragma unroll
    for (int mi = 0; mi < 4; ++mi)
#pragma unroll
      for (int ni = 0; ni < 4; ++ni)
        acc[mi][ni] = __builtin_amdgcn_mfma_f32_16x16x32_bf16(af[mi], bfr[ni], acc[mi][ni], 0, 0, 0);
  }

  // ---- epilogue: h2 = relu(acc + b_c2); fine partials via Wc3 ----
  float part[4][4][3];
#pragma unroll
  for (int mi = 0; mi < 4; ++mi)
#pragma unroll
    for (int r = 0; r < 4; ++r) { part[mi][r][0] = 0.f; part[mi][r][1] = 0.f; part[mi][r][2] = 0.f; }
#pragma unroll
  for (int ni = 0; ni < 4; ++ni) {
    const int n = nblk * 256 + wn + ni * 16 + lm;
    const float bv = bc2[n];
    const float w30 = Wc3[n * 3 + 0];
    const float w31 = Wc3[n * 3 + 1];
    const float w32 = Wc3[n * 3 + 2];
#pragma unroll
    for (int mi = 0; mi < 4; ++mi)
#pragma unroll
      for (int r = 0; r < 4; ++r) {
        float v = fmaxf(acc[mi][ni][r] + bv, 0.f);
        part[mi][r][0] = fmaf(v, w30, part[mi][r][0]);
        part[mi][r][1] = fmaf(v, w31, part[mi][r][1]);
        part[mi][r][2] = fmaf(v, w32, part[mi][r][2]);
      }
  }
  // Per-n-wave slice: each (slice,row,j) written by exactly one lane, once ->
  // plain ds_write (was: 192 contended LDS atomicAdds per wave).
#pragma unroll
  for (int mi = 0; mi < 4; ++mi)
#pragma unroll
    for (int r = 0; r < 4; ++r)
#pragma unroll
      for (int j = 0; j < 3; ++j) {
        float v = red16(part[mi][r][j]);   // DPP 16-lane sum (lm group)
        if (lm == 0) facc4[w & 3][wm + mi * 16 + q * 4 + r][j] = v;
      }
  __syncthreads();
  if (t < 128) {
    const int mm = m0 + t;
    float* fp = fine + (size_t)mm * 3;
    float base[3] = {0.f, 0.f, 0.f};
    if (nblk == 0) {
      const int bb2 = mm >> 14, cc = (mm & 16383) >> 4;
      const float* xq = xf + (bb2 * 1024 + cc) * 3;
#pragma unroll
      for (int j = 0; j < 3; ++j) base[j] = bc3[j] + xq[j];
    }
#pragma unroll
    for (int j = 0; j < 3; ++j) {
      float s = facc4[0][t][j] + facc4[1][t][j] + facc4[2][t][j] + facc4[3][t][j];
      atomicAdd(&fp[j], s + base[j]);
    }
  }
}

extern "C" void kernel_launch(void* const* d_in, const int* in_sizes, int n_in,
                              void* d_out, int out_size, void* d_ws, size_t ws_size,
                              hipStream_t stream) {
  const float* fea = (const float*)d_in[0];
  const float* Wl1 = (const float*)d_in[1];
  const float* bl1 = (const float*)d_in[2];
  const float* Wl2 = (const float*)d_in[3];
  const float* bl2 = (const float*)d_in[4];
  const float* Wc1 = (const float*)d_in[5];
  const float* bc1 = (const float*)d_in[6];
  const float* Wc2 = (const float*)d_in[7];
  const float* bc2 = (const float*)d_in[8];
  const float* Wc3 = (const float*)d_in[9];
  const float* bc3 = (const float*)d_in[10];
  float* xout = (float*)d_out;                // (8,1024,3)
  float* fine = (float*)d_out + 24576;        // (8,16384,3)
  char* ws = (char*)d_ws;
  float* h1  = (float*)ws;                    // 32 KB
  float* xf  = (float*)(ws + 32768);          // 96 KB
  float* gp  = (float*)(ws + 131072);         // 16 KB
  bf16*  W2T = (bf16*)(ws + 147456);          // 512 KB
  float* G   = (float*)(ws + 671744);         // 32 KB

  k_pre<<<1409, 256, 0, stream>>>(fea, Wl1, bl1, Wc1, bc1, Wc2, h1, gp, W2T, G, fine);
  k_lin2<<<192, 256, 0, stream>>>(h1, Wl2, bl2, xf, xout);
  k_gemm<<<2048, 512, 0, stream>>>(W2T, gp, G, Wc1, xf, bc2, Wc3, bc3, fine);
}